// Round 8
// baseline (212.659 us; speedup 1.0000x reference)
//
#include <hip/hip_runtime.h>
#include <hip/hip_bf16.h>

// Problem constants (setup_inputs is fixed)
#define S_LEN 2048
#define BATCH 2
#define EMB   1024
#define NHEAD 16
#define HDIM  64
#define WIN   128

typedef __attribute__((ext_vector_type(8))) short short8;
typedef __attribute__((ext_vector_type(4))) float floatx4;

// Pack two f32 into two RNE-rounded bf16 (lo = a, hi = b).
__device__ __forceinline__ unsigned int pk2bf(float a, float b) {
    unsigned int ua = __builtin_bit_cast(unsigned int, a);
    unsigned int ub = __builtin_bit_cast(unsigned int, b);
    ua += 0x7fffu + ((ua >> 16) & 1u);
    ub += 0x7fffu + ((ub >> 16) & 1u);
    return (ua >> 16) | (ub & 0xffff0000u);
}
__device__ __forceinline__ unsigned short f2bf(float f) {
    unsigned int u = __builtin_bit_cast(unsigned int, f);
    u += 0x7fffu + ((u >> 16) & 1u);
    return (unsigned short)(u >> 16);
}

// Async global->LDS, 16 B per lane. LDS dest = wave-uniform base + lane*16.
__device__ __forceinline__ void gl_lds16(const unsigned short* g, unsigned short* l) {
    __builtin_amdgcn_global_load_lds(
        (const __attribute__((address_space(1))) unsigned int*)g,
        (__attribute__((address_space(3))) unsigned int*)l,
        16, 0, 0);
}

// ---------------------------------------------------------------------------
// Convert pass: f32 -> bf16 for x(q,k,v), in_proj_w, out_proj_w.
// ---------------------------------------------------------------------------
#define QKV_UNITS 524288          // 4194304/8
#define WI_UNITS  393216          // 3145728/8
#define WO_UNITS  131072          // 1048576/8

__global__ __launch_bounds__(256)
void convert_kernel(const float* __restrict__ xq, const float* __restrict__ xk,
                    const float* __restrict__ xv, const float* __restrict__ wi,
                    const float* __restrict__ wo,
                    unsigned short* __restrict__ xqb, unsigned short* __restrict__ xkb,
                    unsigned short* __restrict__ xvb, unsigned short* __restrict__ wib,
                    unsigned short* __restrict__ wob)
{
    const size_t u = (size_t)blockIdx.x * 256 + threadIdx.x;
    const float* src;
    unsigned short* dst;
    size_t off;
    if (u < 3 * (size_t)QKV_UNITS) {
        const int which = (int)(u / QKV_UNITS);
        off = (u % QKV_UNITS) * 8;
        src = (which == 0) ? xq : (which == 1) ? xk : xv;
        dst = (which == 0) ? xqb : (which == 1) ? xkb : xvb;
    } else if (u < 3 * (size_t)QKV_UNITS + WI_UNITS) {
        off = (u - 3 * (size_t)QKV_UNITS) * 8;
        src = wi; dst = wib;
    } else {
        off = (u - (3 * (size_t)QKV_UNITS + WI_UNITS)) * 8;
        src = wo; dst = wob;
    }
    float4 a = *reinterpret_cast<const float4*>(src + off);
    float4 b = *reinterpret_cast<const float4*>(src + off + 4);
    uint4 p = {pk2bf(a.x, a.y), pk2bf(a.z, a.w), pk2bf(b.x, b.y), pk2bf(b.z, b.w)};
    *reinterpret_cast<uint4*>(dst + off) = p;
}

// ---------------------------------------------------------------------------
// QKV projection, bf16 MFMA GEMM. 128x128 tile, BK=64, XCD-swizzled 1D grid
// (bid = z*256 + x*32 + y -> XCD = y%8). global_load_lds staging with
// XOR-swizzled k-segments: LDS[row][seg] holds global k-seg (seg ^ (row&7)),
// so ds_read_b128 start-banks form a bijection over the 8 bank-quads
// (2-way only = free). Reader applies the same XOR.
// Outputs bf16: q,k as [B,H,S,D] (q scaled 0.125), v transposed [B,H,D,S].
// ---------------------------------------------------------------------------
__global__ __launch_bounds__(256)
void qkv_gemm_kernel(const unsigned short* __restrict__ xqb,
                     const unsigned short* __restrict__ xkb,
                     const unsigned short* __restrict__ xvb,
                     const unsigned short* __restrict__ wib,   // [3E, E] bf16
                     const float* __restrict__ bias,           // [3E] f32
                     unsigned short* __restrict__ qo,
                     unsigned short* __restrict__ ko,
                     unsigned short* __restrict__ vto)
{
    __shared__ unsigned short As[128 * 64];
    __shared__ unsigned short Bs[128 * 64];

    const int bid  = blockIdx.x;
    const int which = bid >> 8;            // z
    const int bx   = (bid >> 5) & 7;       // col-tile
    const int by   = bid & 31;             // row-panel (XCD key)

    const unsigned short* A = (which == 0) ? xqb : (which == 1) ? xkb : xvb;
    const unsigned short* W = wib + (size_t)which * EMB * EMB;
    const float* bv = bias + which * EMB;
    const float scale = (which == 0) ? 0.125f : 1.0f;

    const int tid  = threadIdx.x;
    const int lane = tid & 63;
    const int wave = tid >> 6;
    const int quad = lane >> 4;
    const int c16  = lane & 15;
    const int wm   = (wave & 1) << 6;
    const int wn   = (wave >> 1) << 6;

    const int rowBase = by * 128;
    const int colBase = bx * 128;

    // Staging: chunk = 8 rows x 64 ushorts = 1 KB (one gl_lds16 per wave).
    // A: chunks 0..15, B: chunks 0..15; wave w takes 4 of each.
    const int lrow = lane >> 3;                  // 0..7 within chunk
    const int lseg = ((lane & 7) ^ lrow) << 3;   // XOR-swizzled k-seg (ushorts)

    floatx4 acc[4][4];
    #pragma unroll
    for (int i = 0; i < 4; ++i)
        #pragma unroll
        for (int j = 0; j < 4; ++j)
            acc[i][j] = (floatx4){0.f, 0.f, 0.f, 0.f};

    const int rsw = (c16 & 7) << 3;   // read-side XOR key * 8 (row&7 == c16&7)

    for (int k0 = 0; k0 < EMB; k0 += 64) {
        __syncthreads();
        #pragma unroll
        for (int t = 0; t < 4; ++t) {
            const int c = wave * 4 + t;
            const int row = c * 8 + lrow;
            gl_lds16(A + (size_t)(rowBase + row) * EMB + k0 + lseg, &As[c * 512]);
            gl_lds16(W + (size_t)(colBase + row) * EMB + k0 + lseg, &Bs[c * 512]);
        }
        __syncthreads();

        #pragma unroll
        for (int kh = 0; kh < 2; ++kh) {
            const int soff = (((kh * 4 + quad) << 3) ^ rsw);
            short8 af[4], bf[4];
            #pragma unroll
            for (int mi = 0; mi < 4; ++mi)
                af[mi] = *reinterpret_cast<const short8*>(
                    &As[(wm + mi * 16 + c16) * 64 + soff]);
            #pragma unroll
            for (int ni = 0; ni < 4; ++ni)
                bf[ni] = *reinterpret_cast<const short8*>(
                    &Bs[(wn + ni * 16 + c16) * 64 + soff]);

            #pragma unroll
            for (int mi = 0; mi < 4; ++mi)
                #pragma unroll
                for (int ni = 0; ni < 4; ++ni)
                    acc[mi][ni] = __builtin_amdgcn_mfma_f32_16x16x32_bf16(
                        af[mi], bf[ni], acc[mi][ni], 0, 0, 0);
        }
    }

    // Epilogue -> bf16. D[m = quad*4+r][n = c16] per 16x16 tile.
    #pragma unroll
    for (int ni = 0; ni < 4; ++ni) {
        const int n_full = colBase + wn + ni * 16 + c16;   // 0..1023
        const float bb = bv[n_full];
        const int h = n_full >> 6;
        const int d = n_full & 63;
        #pragma unroll
        for (int mi = 0; mi < 4; ++mi) {
            #pragma unroll
            for (int r = 0; r < 4; ++r) {
                const int m_g = rowBase + wm + mi * 16 + quad * 4 + r;
                const int s   = m_g >> 1;      // m = s*B + b
                const int b   = m_g & 1;
                const int bh  = b * NHEAD + h;
                const unsigned short val = f2bf((acc[mi][ni][r] + bb) * scale);
                if (which == 2)
                    vto[((size_t)bh * HDIM + d) * S_LEN + s] = val;
                else if (which == 0)
                    qo[((size_t)bh * S_LEN + s) * HDIM + d] = val;
                else
                    ko[((size_t)bh * S_LEN + s) * HDIM + d] = val;
            }
        }
    }
}

// ---------------------------------------------------------------------------
// MFMA flash attention over the band. 1D grid, XCD-swizzled (bid = sx*32+bh).
// ctx out bf16.
// ---------------------------------------------------------------------------
#define AT_STRIDE 72   // ushorts per LDS row (144B)

__global__ __launch_bounds__(256)
void attn_mfma_kernel(const unsigned short* __restrict__ q,
                      const unsigned short* __restrict__ k,
                      const unsigned short* __restrict__ vt,
                      unsigned short* __restrict__ ctx)
{
    __shared__ unsigned short Qs[64 * AT_STRIDE];
    __shared__ unsigned short Ks[64 * AT_STRIDE];
    __shared__ unsigned short Vts[64 * AT_STRIDE];
    __shared__ unsigned short Ps[64 * AT_STRIDE];

    const int bid = blockIdx.x;
    const int bh  = bid & 31;
    const int s0  = (bid >> 5) * 64;
    const int tid = threadIdx.x;
    const int lane = tid & 63;
    const int wave = tid >> 6;
    const int quad = lane >> 4;
    const int c16  = lane & 15;

    const size_t base_qk = ((size_t)bh * S_LEN) * HDIM;
    const size_t base_vt = ((size_t)bh * HDIM) * S_LEN;

    const int srow = tid >> 2;
    const int sseg = (tid & 3) << 4;
    {
        const unsigned short* src = q + base_qk + (size_t)(s0 + srow) * HDIM + sseg;
        uint4 v0 = *reinterpret_cast<const uint4*>(src);
        uint4 v1 = *reinterpret_cast<const uint4*>(src + 8);
        *reinterpret_cast<uint4*>(&Qs[srow * AT_STRIDE + sseg])     = v0;
        *reinterpret_cast<uint4*>(&Qs[srow * AT_STRIDE + sseg + 8]) = v1;
    }

    float m_[4], l_[4];
    floatx4 ob[4];
    #pragma unroll
    for (int r = 0; r < 4; ++r) { m_[r] = -1.0e30f; l_[r] = 0.f; }
    #pragma unroll
    for (int dt = 0; dt < 4; ++dt) ob[dt] = (floatx4){0.f, 0.f, 0.f, 0.f};

    int c0 = s0 - 128; if (c0 < 0) c0 = 0;
    int c1 = s0 + 192; if (c1 > S_LEN) c1 = S_LEN;

    for (int cb = c0; cb < c1; cb += 64) {
        __syncthreads();
        {
            const unsigned short* ksrc = k + base_qk + (size_t)(cb + srow) * HDIM + sseg;
            const unsigned short* vsrc = vt + base_vt + (size_t)srow * S_LEN + cb + sseg;
            uint4 k0v = *reinterpret_cast<const uint4*>(ksrc);
            uint4 k1v = *reinterpret_cast<const uint4*>(ksrc + 8);
            uint4 v0v = *reinterpret_cast<const uint4*>(vsrc);
            uint4 v1v = *reinterpret_cast<const uint4*>(vsrc + 8);
            *reinterpret_cast<uint4*>(&Ks[srow * AT_STRIDE + sseg])      = k0v;
            *reinterpret_cast<uint4*>(&Ks[srow * AT_STRIDE + sseg + 8])  = k1v;
            *reinterpret_cast<uint4*>(&Vts[srow * AT_STRIDE + sseg])     = v0v;
            *reinterpret_cast<uint4*>(&Vts[srow * AT_STRIDE + sseg + 8]) = v1v;
        }
        __syncthreads();

        floatx4 sc[4];
        #pragma unroll
        for (int jt = 0; jt < 4; ++jt) sc[jt] = (floatx4){0.f, 0.f, 0.f, 0.f};
        {
            short8 af0 = *reinterpret_cast<const short8*>(
                &Qs[(wave * 16 + c16) * AT_STRIDE + quad * 8]);
            short8 af1 = *reinterpret_cast<const short8*>(
                &Qs[(wave * 16 + c16) * AT_STRIDE + 32 + quad * 8]);
            #pragma unroll
            for (int jt = 0; jt < 4; ++jt) {
                short8 bf0 = *reinterpret_cast<const short8*>(
                    &Ks[(jt * 16 + c16) * AT_STRIDE + quad * 8]);
                short8 bf1 = *reinterpret_cast<const short8*>(
                    &Ks[(jt * 16 + c16) * AT_STRIDE + 32 + quad * 8]);
                sc[jt] = __builtin_amdgcn_mfma_f32_16x16x32_bf16(af0, bf0, sc[jt], 0, 0, 0);
                sc[jt] = __builtin_amdgcn_mfma_f32_16x16x32_bf16(af1, bf1, sc[jt], 0, 0, 0);
            }
        }

        #pragma unroll
        for (int r = 0; r < 4; ++r) {
            const int qg = s0 + wave * 16 + quad * 4 + r;
            float rm = -3.0e38f;
            #pragma unroll
            for (int jt = 0; jt < 4; ++jt) {
                const int jg = cb + jt * 16 + c16;
                float x = sc[jt][r];
                if (jg < qg - WIN || jg >= qg + WIN) x = -3.0e38f;
                sc[jt][r] = x;
                rm = fmaxf(rm, x);
            }
            rm = fmaxf(rm, __shfl_xor(rm, 1));
            rm = fmaxf(rm, __shfl_xor(rm, 2));
            rm = fmaxf(rm, __shfl_xor(rm, 4));
            rm = fmaxf(rm, __shfl_xor(rm, 8));
            const float mn    = fmaxf(m_[r], rm);
            const float alpha = __expf(m_[r] - mn);
            float rs = 0.f;
            #pragma unroll
            for (int jt = 0; jt < 4; ++jt) {
                const float p = __expf(sc[jt][r] - mn);
                sc[jt][r] = p;
                rs += p;
            }
            rs += __shfl_xor(rs, 1);
            rs += __shfl_xor(rs, 2);
            rs += __shfl_xor(rs, 4);
            rs += __shfl_xor(rs, 8);
            l_[r] = l_[r] * alpha + rs;
            m_[r] = mn;
            #pragma unroll
            for (int dt = 0; dt < 4; ++dt) ob[dt][r] *= alpha;
        }

        #pragma unroll
        for (int jt = 0; jt < 4; ++jt)
            #pragma unroll
            for (int r = 0; r < 4; ++r)
                Ps[(wave * 16 + quad * 4 + r) * AT_STRIDE + jt * 16 + c16] =
                    f2bf(sc[jt][r]);

        {
            short8 pa0 = *reinterpret_cast<const short8*>(
                &Ps[(wave * 16 + c16) * AT_STRIDE + quad * 8]);
            short8 pa1 = *reinterpret_cast<const short8*>(
                &Ps[(wave * 16 + c16) * AT_STRIDE + 32 + quad * 8]);
            #pragma unroll
            for (int dt = 0; dt < 4; ++dt) {
                short8 bv0 = *reinterpret_cast<const short8*>(
                    &Vts[(dt * 16 + c16) * AT_STRIDE + quad * 8]);
                short8 bv1 = *reinterpret_cast<const short8*>(
                    &Vts[(dt * 16 + c16) * AT_STRIDE + 32 + quad * 8]);
                ob[dt] = __builtin_amdgcn_mfma_f32_16x16x32_bf16(pa0, bv0, ob[dt], 0, 0, 0);
                ob[dt] = __builtin_amdgcn_mfma_f32_16x16x32_bf16(pa1, bv1, ob[dt], 0, 0, 0);
            }
        }
    }

    // Epilogue: O/l -> ctx [S,B,E] bf16.
    const int b = bh >> 4;
    const int h = bh & 15;
    #pragma unroll
    for (int r = 0; r < 4; ++r) {
        const int sg  = s0 + wave * 16 + quad * 4 + r;
        const float inv = 1.0f / l_[r];
        #pragma unroll
        for (int dt = 0; dt < 4; ++dt) {
            const int d = dt * 16 + c16;
            ctx[((size_t)(sg * BATCH + b) << 10) + (h << 6) + d] = f2bf(ob[dt][r] * inv);
        }
    }
}

// ---------------------------------------------------------------------------
// Output projection, BK=64 + XOR-swizzle, XCD-swizzled 1D grid (bid=x*32+y).
// ctx: [4096,1024] bf16, W: [1024,1024] bf16, out: [S,B,E] f32.
// ---------------------------------------------------------------------------
__global__ __launch_bounds__(256)
void out_gemm_kernel(const unsigned short* __restrict__ ctxb,
                     const unsigned short* __restrict__ wob,
                     const float* __restrict__ bias,
                     float* __restrict__ out)
{
    __shared__ unsigned short As[128 * 64];
    __shared__ unsigned short Bs[128 * 64];

    const int bid = blockIdx.x;
    const int bx  = bid >> 5;
    const int by  = bid & 31;

    const int tid  = threadIdx.x;
    const int lane = tid & 63;
    const int wave = tid >> 6;
    const int quad = lane >> 4;
    const int c16  = lane & 15;
    const int wm   = (wave & 1) << 6;
    const int wn   = (wave >> 1) << 6;

    const int rowBase = by * 128;
    const int colBase = bx * 128;

    const int lrow = lane >> 3;
    const int lseg = ((lane & 7) ^ lrow) << 3;

    floatx4 acc[4][4];
    #pragma unroll
    for (int i = 0; i < 4; ++i)
        #pragma unroll
        for (int j = 0; j < 4; ++j)
            acc[i][j] = (floatx4){0.f, 0.f, 0.f, 0.f};

    const int rsw = (c16 & 7) << 3;

    for (int k0 = 0; k0 < EMB; k0 += 64) {
        __syncthreads();
        #pragma unroll
        for (int t = 0; t < 4; ++t) {
            const int c = wave * 4 + t;
            const int row = c * 8 + lrow;
            gl_lds16(ctxb + (size_t)(rowBase + row) * EMB + k0 + lseg, &As[c * 512]);
            gl_lds16(wob  + (size_t)(colBase + row) * EMB + k0 + lseg, &Bs[c * 512]);
        }
        __syncthreads();

        #pragma unroll
        for (int kh = 0; kh < 2; ++kh) {
            const int soff = (((kh * 4 + quad) << 3) ^ rsw);
            short8 af[4], bf[4];
            #pragma unroll
            for (int mi = 0; mi < 4; ++mi)
                af[mi] = *reinterpret_cast<const short8*>(
                    &As[(wm + mi * 16 + c16) * 64 + soff]);
            #pragma unroll
            for (int ni = 0; ni < 4; ++ni)
                bf[ni] = *reinterpret_cast<const short8*>(
                    &Bs[(wn + ni * 16 + c16) * 64 + soff]);

            #pragma unroll
            for (int mi = 0; mi < 4; ++mi)
                #pragma unroll
                for (int ni = 0; ni < 4; ++ni)
                    acc[mi][ni] = __builtin_amdgcn_mfma_f32_16x16x32_bf16(
                        af[mi], bf[ni], acc[mi][ni], 0, 0, 0);
        }
    }

    #pragma unroll
    for (int ni = 0; ni < 4; ++ni) {
        const int n_full = colBase + wn + ni * 16 + c16;
        const float bb = bias[n_full];
        #pragma unroll
        for (int mi = 0; mi < 4; ++mi) {
            #pragma unroll
            for (int r = 0; r < 4; ++r) {
                const int m_g = rowBase + wm + mi * 16 + quad * 4 + r;
                out[(size_t)m_g * EMB + n_full] = acc[mi][ni][r] + bb;
            }
        }
    }
}

// ---------------------------------------------------------------------------
extern "C" void kernel_launch(void* const* d_in, const int* in_sizes, int n_in,
                              void* d_out, int out_size, void* d_ws, size_t ws_size,
                              hipStream_t stream) {
    const float* query = (const float*)d_in[0];
    const float* key   = (const float*)d_in[1];
    const float* value = (const float*)d_in[2];
    const float* in_w  = (const float*)d_in[3];
    const float* in_b  = (const float*)d_in[4];
    const float* out_w = (const float*)d_in[5];
    const float* out_b = (const float*)d_in[6];

    const size_t PLANE = (size_t)BATCH * NHEAD * S_LEN * HDIM;  // 4194304
    unsigned short* xqb = (unsigned short*)d_ws;
    unsigned short* xkb = xqb + PLANE;
    unsigned short* xvb = xkb + PLANE;
    unsigned short* wib = xvb + PLANE;                 // 3*EMB*EMB
    unsigned short* wob = wib + (size_t)3 * EMB * EMB; // EMB*EMB
    unsigned short* qo  = wob + (size_t)EMB * EMB;
    unsigned short* ko  = qo + PLANE;
    unsigned short* vto = ko + PLANE;
    unsigned short* cw  = vto + PLANE;

    convert_kernel<<<8192, 256, 0, stream>>>(query, key, value, in_w, out_w,
                                             xqb, xkb, xvb, wib, wob);

    qkv_gemm_kernel<<<768, 256, 0, stream>>>(xqb, xkb, xvb, wib, in_b, qo, ko, vto);

    attn_mfma_kernel<<<1024, 256, 0, stream>>>(qo, ko, vto, cw);

    out_gemm_kernel<<<256, 256, 0, stream>>>(cw, wob, out_b, (float*)d_out);
}

// Round 9
// 199.396 us; speedup vs baseline: 1.0665x; 1.0665x over previous
//
#include <hip/hip_runtime.h>
#include <hip/hip_bf16.h>

// Problem constants (setup_inputs is fixed)
#define S_LEN 2048
#define BATCH 2
#define EMB   1024
#define NHEAD 16
#define HDIM  64
#define WIN   128

typedef __attribute__((ext_vector_type(8))) short short8;
typedef __attribute__((ext_vector_type(4))) float floatx4;

// Pack two f32 into two RNE-rounded bf16 (lo = a, hi = b).
__device__ __forceinline__ unsigned int pk2bf(float a, float b) {
    unsigned int ua = __builtin_bit_cast(unsigned int, a);
    unsigned int ub = __builtin_bit_cast(unsigned int, b);
    ua += 0x7fffu + ((ua >> 16) & 1u);
    ub += 0x7fffu + ((ub >> 16) & 1u);
    return (ua >> 16) | (ub & 0xffff0000u);
}
__device__ __forceinline__ unsigned short f2bf(float f) {
    unsigned int u = __builtin_bit_cast(unsigned int, f);
    u += 0x7fffu + ((u >> 16) & 1u);
    return (unsigned short)(u >> 16);
}

// Async global->LDS, 16 B per lane. LDS dest = wave-uniform base + lane*16.
__device__ __forceinline__ void gl_lds16(const unsigned short* g, unsigned short* l) {
    __builtin_amdgcn_global_load_lds(
        (const __attribute__((address_space(1))) unsigned int*)g,
        (__attribute__((address_space(3))) unsigned int*)l,
        16, 0, 0);
}

// ---------------------------------------------------------------------------
// Convert pass: f32 -> bf16 for x(q,k,v), in_proj_w, out_proj_w.
// ---------------------------------------------------------------------------
#define QKV_UNITS 524288          // 4194304/8
#define WI_UNITS  393216          // 3145728/8
#define WO_UNITS  131072          // 1048576/8

__global__ __launch_bounds__(256)
void convert_kernel(const float* __restrict__ xq, const float* __restrict__ xk,
                    const float* __restrict__ xv, const float* __restrict__ wi,
                    const float* __restrict__ wo,
                    unsigned short* __restrict__ xqb, unsigned short* __restrict__ xkb,
                    unsigned short* __restrict__ xvb, unsigned short* __restrict__ wib,
                    unsigned short* __restrict__ wob)
{
    const size_t u = (size_t)blockIdx.x * 256 + threadIdx.x;
    const float* src;
    unsigned short* dst;
    size_t off;
    if (u < 3 * (size_t)QKV_UNITS) {
        const int which = (int)(u / QKV_UNITS);
        off = (u % QKV_UNITS) * 8;
        src = (which == 0) ? xq : (which == 1) ? xk : xv;
        dst = (which == 0) ? xqb : (which == 1) ? xkb : xvb;
    } else if (u < 3 * (size_t)QKV_UNITS + WI_UNITS) {
        off = (u - 3 * (size_t)QKV_UNITS) * 8;
        src = wi; dst = wib;
    } else {
        off = (u - (3 * (size_t)QKV_UNITS + WI_UNITS)) * 8;
        src = wo; dst = wob;
    }
    float4 a = *reinterpret_cast<const float4*>(src + off);
    float4 b = *reinterpret_cast<const float4*>(src + off + 4);
    uint4 p = {pk2bf(a.x, a.y), pk2bf(a.z, a.w), pk2bf(b.x, b.y), pk2bf(b.z, b.w)};
    *reinterpret_cast<uint4*>(dst + off) = p;
}

// ---------------------------------------------------------------------------
// QKV projection, bf16 MFMA GEMM. 128x128 tile, BK=32 (16 KB LDS, ~2 blk/CU),
// XCD-swizzled 1D grid (bid = z*256 + x*32 + y -> XCD = y%8).
// global_load_lds staging with XOR-swizzled 16B k-segments:
// LDS slot s of row r holds global k-seg s^(r&3); reader uses slot q^(r&3).
// Start bank-quad = 4*(r&1) + perm -> all 8 quads hit 2x (2-way = free).
// Outputs bf16: q,k as [B,H,S,D] (q scaled 0.125), v transposed [B,H,D,S].
// ---------------------------------------------------------------------------
__global__ __launch_bounds__(256)
void qkv_gemm_kernel(const unsigned short* __restrict__ xqb,
                     const unsigned short* __restrict__ xkb,
                     const unsigned short* __restrict__ xvb,
                     const unsigned short* __restrict__ wib,   // [3E, E] bf16
                     const float* __restrict__ bias,           // [3E] f32
                     unsigned short* __restrict__ qo,
                     unsigned short* __restrict__ ko,
                     unsigned short* __restrict__ vto)
{
    __shared__ unsigned short As[128 * 32];
    __shared__ unsigned short Bs[128 * 32];

    const int bid  = blockIdx.x;
    const int which = bid >> 8;            // z
    const int bx   = (bid >> 5) & 7;       // col-tile
    const int by   = bid & 31;             // row-panel (XCD key)

    const unsigned short* A = (which == 0) ? xqb : (which == 1) ? xkb : xvb;
    const unsigned short* W = wib + (size_t)which * EMB * EMB;
    const float* bv = bias + which * EMB;
    const float scale = (which == 0) ? 0.125f : 1.0f;

    const int tid  = threadIdx.x;
    const int lane = tid & 63;
    const int wave = tid >> 6;
    const int quad = lane >> 4;
    const int c16  = lane & 15;
    const int wm   = (wave & 1) << 6;
    const int wn   = (wave >> 1) << 6;

    const int rowBase = by * 128;
    const int colBase = bx * 128;

    // Staging: chunk c = 16 rows x 32 ushorts; lane -> (lrow, XOR-perm seg).
    const int lrow = lane >> 2;                        // 0..15 within chunk
    const int lseg = (((lane & 3) ^ (lrow & 3)) << 3); // permuted k-seg (ushorts)

    floatx4 acc[4][4];
    #pragma unroll
    for (int i = 0; i < 4; ++i)
        #pragma unroll
        for (int j = 0; j < 4; ++j)
            acc[i][j] = (floatx4){0.f, 0.f, 0.f, 0.f};

    const int rxor = c16 & 3;   // read-side XOR key (row&3 == c16&3)

    for (int k0 = 0; k0 < EMB; k0 += 32) {
        __syncthreads();
        #pragma unroll
        for (int t = 0; t < 2; ++t) {
            const int c = wave * 2 + t;
            const int row = c * 16 + lrow;
            gl_lds16(A + (size_t)(rowBase + row) * EMB + k0 + lseg, &As[c * 512]);
            gl_lds16(W + (size_t)(colBase + row) * EMB + k0 + lseg, &Bs[c * 512]);
        }
        __syncthreads();

        const int soff = ((quad ^ rxor) << 3);
        short8 af[4], bf[4];
        #pragma unroll
        for (int mi = 0; mi < 4; ++mi)
            af[mi] = *reinterpret_cast<const short8*>(
                &As[(wm + mi * 16 + c16) * 32 + soff]);
        #pragma unroll
        for (int ni = 0; ni < 4; ++ni)
            bf[ni] = *reinterpret_cast<const short8*>(
                &Bs[(wn + ni * 16 + c16) * 32 + soff]);

        #pragma unroll
        for (int mi = 0; mi < 4; ++mi)
            #pragma unroll
            for (int ni = 0; ni < 4; ++ni)
                acc[mi][ni] = __builtin_amdgcn_mfma_f32_16x16x32_bf16(
                    af[mi], bf[ni], acc[mi][ni], 0, 0, 0);
    }

    // Epilogue -> bf16. D[m = quad*4+r][n = c16] per 16x16 tile.
    #pragma unroll
    for (int ni = 0; ni < 4; ++ni) {
        const int n_full = colBase + wn + ni * 16 + c16;   // 0..1023
        const float bb = bv[n_full];
        const int h = n_full >> 6;
        const int d = n_full & 63;
        #pragma unroll
        for (int mi = 0; mi < 4; ++mi) {
            #pragma unroll
            for (int r = 0; r < 4; ++r) {
                const int m_g = rowBase + wm + mi * 16 + quad * 4 + r;
                const int s   = m_g >> 1;      // m = s*B + b
                const int b   = m_g & 1;
                const int bh  = b * NHEAD + h;
                const unsigned short val = f2bf((acc[mi][ni][r] + bb) * scale);
                if (which == 2)
                    vto[((size_t)bh * HDIM + d) * S_LEN + s] = val;
                else if (which == 0)
                    qo[((size_t)bh * S_LEN + s) * HDIM + d] = val;
                else
                    ko[((size_t)bh * S_LEN + s) * HDIM + d] = val;
            }
        }
    }
}

// ---------------------------------------------------------------------------
// MFMA flash attention over the band. 1D grid, XCD-swizzled (bid = sx*32+bh).
// ctx out bf16.
// ---------------------------------------------------------------------------
#define AT_STRIDE 72   // ushorts per LDS row (144B)

__global__ __launch_bounds__(256)
void attn_mfma_kernel(const unsigned short* __restrict__ q,
                      const unsigned short* __restrict__ k,
                      const unsigned short* __restrict__ vt,
                      unsigned short* __restrict__ ctx)
{
    __shared__ unsigned short Qs[64 * AT_STRIDE];
    __shared__ unsigned short Ks[64 * AT_STRIDE];
    __shared__ unsigned short Vts[64 * AT_STRIDE];
    __shared__ unsigned short Ps[64 * AT_STRIDE];

    const int bid = blockIdx.x;
    const int bh  = bid & 31;
    const int s0  = (bid >> 5) * 64;
    const int tid = threadIdx.x;
    const int lane = tid & 63;
    const int wave = tid >> 6;
    const int quad = lane >> 4;
    const int c16  = lane & 15;

    const size_t base_qk = ((size_t)bh * S_LEN) * HDIM;
    const size_t base_vt = ((size_t)bh * HDIM) * S_LEN;

    const int srow = tid >> 2;
    const int sseg = (tid & 3) << 4;
    {
        const unsigned short* src = q + base_qk + (size_t)(s0 + srow) * HDIM + sseg;
        uint4 v0 = *reinterpret_cast<const uint4*>(src);
        uint4 v1 = *reinterpret_cast<const uint4*>(src + 8);
        *reinterpret_cast<uint4*>(&Qs[srow * AT_STRIDE + sseg])     = v0;
        *reinterpret_cast<uint4*>(&Qs[srow * AT_STRIDE + sseg + 8]) = v1;
    }

    float m_[4], l_[4];
    floatx4 ob[4];
    #pragma unroll
    for (int r = 0; r < 4; ++r) { m_[r] = -1.0e30f; l_[r] = 0.f; }
    #pragma unroll
    for (int dt = 0; dt < 4; ++dt) ob[dt] = (floatx4){0.f, 0.f, 0.f, 0.f};

    int c0 = s0 - 128; if (c0 < 0) c0 = 0;
    int c1 = s0 + 192; if (c1 > S_LEN) c1 = S_LEN;

    for (int cb = c0; cb < c1; cb += 64) {
        __syncthreads();
        {
            const unsigned short* ksrc = k + base_qk + (size_t)(cb + srow) * HDIM + sseg;
            const unsigned short* vsrc = vt + base_vt + (size_t)srow * S_LEN + cb + sseg;
            uint4 k0v = *reinterpret_cast<const uint4*>(ksrc);
            uint4 k1v = *reinterpret_cast<const uint4*>(ksrc + 8);
            uint4 v0v = *reinterpret_cast<const uint4*>(vsrc);
            uint4 v1v = *reinterpret_cast<const uint4*>(vsrc + 8);
            *reinterpret_cast<uint4*>(&Ks[srow * AT_STRIDE + sseg])      = k0v;
            *reinterpret_cast<uint4*>(&Ks[srow * AT_STRIDE + sseg + 8])  = k1v;
            *reinterpret_cast<uint4*>(&Vts[srow * AT_STRIDE + sseg])     = v0v;
            *reinterpret_cast<uint4*>(&Vts[srow * AT_STRIDE + sseg + 8]) = v1v;
        }
        __syncthreads();

        floatx4 sc[4];
        #pragma unroll
        for (int jt = 0; jt < 4; ++jt) sc[jt] = (floatx4){0.f, 0.f, 0.f, 0.f};
        {
            short8 af0 = *reinterpret_cast<const short8*>(
                &Qs[(wave * 16 + c16) * AT_STRIDE + quad * 8]);
            short8 af1 = *reinterpret_cast<const short8*>(
                &Qs[(wave * 16 + c16) * AT_STRIDE + 32 + quad * 8]);
            #pragma unroll
            for (int jt = 0; jt < 4; ++jt) {
                short8 bf0 = *reinterpret_cast<const short8*>(
                    &Ks[(jt * 16 + c16) * AT_STRIDE + quad * 8]);
                short8 bf1 = *reinterpret_cast<const short8*>(
                    &Ks[(jt * 16 + c16) * AT_STRIDE + 32 + quad * 8]);
                sc[jt] = __builtin_amdgcn_mfma_f32_16x16x32_bf16(af0, bf0, sc[jt], 0, 0, 0);
                sc[jt] = __builtin_amdgcn_mfma_f32_16x16x32_bf16(af1, bf1, sc[jt], 0, 0, 0);
            }
        }

        #pragma unroll
        for (int r = 0; r < 4; ++r) {
            const int qg = s0 + wave * 16 + quad * 4 + r;
            float rm = -3.0e38f;
            #pragma unroll
            for (int jt = 0; jt < 4; ++jt) {
                const int jg = cb + jt * 16 + c16;
                float x = sc[jt][r];
                if (jg < qg - WIN || jg >= qg + WIN) x = -3.0e38f;
                sc[jt][r] = x;
                rm = fmaxf(rm, x);
            }
            rm = fmaxf(rm, __shfl_xor(rm, 1));
            rm = fmaxf(rm, __shfl_xor(rm, 2));
            rm = fmaxf(rm, __shfl_xor(rm, 4));
            rm = fmaxf(rm, __shfl_xor(rm, 8));
            const float mn    = fmaxf(m_[r], rm);
            const float alpha = __expf(m_[r] - mn);
            float rs = 0.f;
            #pragma unroll
            for (int jt = 0; jt < 4; ++jt) {
                const float p = __expf(sc[jt][r] - mn);
                sc[jt][r] = p;
                rs += p;
            }
            rs += __shfl_xor(rs, 1);
            rs += __shfl_xor(rs, 2);
            rs += __shfl_xor(rs, 4);
            rs += __shfl_xor(rs, 8);
            l_[r] = l_[r] * alpha + rs;
            m_[r] = mn;
            #pragma unroll
            for (int dt = 0; dt < 4; ++dt) ob[dt][r] *= alpha;
        }

        #pragma unroll
        for (int jt = 0; jt < 4; ++jt)
            #pragma unroll
            for (int r = 0; r < 4; ++r)
                Ps[(wave * 16 + quad * 4 + r) * AT_STRIDE + jt * 16 + c16] =
                    f2bf(sc[jt][r]);

        {
            short8 pa0 = *reinterpret_cast<const short8*>(
                &Ps[(wave * 16 + c16) * AT_STRIDE + quad * 8]);
            short8 pa1 = *reinterpret_cast<const short8*>(
                &Ps[(wave * 16 + c16) * AT_STRIDE + 32 + quad * 8]);
            #pragma unroll
            for (int dt = 0; dt < 4; ++dt) {
                short8 bv0 = *reinterpret_cast<const short8*>(
                    &Vts[(dt * 16 + c16) * AT_STRIDE + quad * 8]);
                short8 bv1 = *reinterpret_cast<const short8*>(
                    &Vts[(dt * 16 + c16) * AT_STRIDE + 32 + quad * 8]);
                ob[dt] = __builtin_amdgcn_mfma_f32_16x16x32_bf16(pa0, bv0, ob[dt], 0, 0, 0);
                ob[dt] = __builtin_amdgcn_mfma_f32_16x16x32_bf16(pa1, bv1, ob[dt], 0, 0, 0);
            }
        }
    }

    // Epilogue: O/l -> ctx [S,B,E] bf16.
    const int b = bh >> 4;
    const int h = bh & 15;
    #pragma unroll
    for (int r = 0; r < 4; ++r) {
        const int sg  = s0 + wave * 16 + quad * 4 + r;
        const float inv = 1.0f / l_[r];
        #pragma unroll
        for (int dt = 0; dt < 4; ++dt) {
            const int d = dt * 16 + c16;
            ctx[((size_t)(sg * BATCH + b) << 10) + (h << 6) + d] = f2bf(ob[dt][r] * inv);
        }
    }
}

// ---------------------------------------------------------------------------
// Output projection, BK=32 + XOR swizzle, XCD-swizzled 1D grid (bid=x*32+y).
// ctx: [4096,1024] bf16, W: [1024,1024] bf16, out: [S,B,E] f32.
// ---------------------------------------------------------------------------
__global__ __launch_bounds__(256)
void out_gemm_kernel(const unsigned short* __restrict__ ctxb,
                     const unsigned short* __restrict__ wob,
                     const float* __restrict__ bias,
                     float* __restrict__ out)
{
    __shared__ unsigned short As[128 * 32];
    __shared__ unsigned short Bs[128 * 32];

    const int bid = blockIdx.x;
    const int bx  = bid >> 5;
    const int by  = bid & 31;

    const int tid  = threadIdx.x;
    const int lane = tid & 63;
    const int wave = tid >> 6;
    const int quad = lane >> 4;
    const int c16  = lane & 15;
    const int wm   = (wave & 1) << 6;
    const int wn   = (wave >> 1) << 6;

    const int rowBase = by * 128;
    const int colBase = bx * 128;

    const int lrow = lane >> 2;
    const int lseg = (((lane & 3) ^ (lrow & 3)) << 3);

    floatx4 acc[4][4];
    #pragma unroll
    for (int i = 0; i < 4; ++i)
        #pragma unroll
        for (int j = 0; j < 4; ++j)
            acc[i][j] = (floatx4){0.f, 0.f, 0.f, 0.f};

    const int rxor = c16 & 3;

    for (int k0 = 0; k0 < EMB; k0 += 32) {
        __syncthreads();
        #pragma unroll
        for (int t = 0; t < 2; ++t) {
            const int c = wave * 2 + t;
            const int row = c * 16 + lrow;
            gl_lds16(ctxb + (size_t)(rowBase + row) * EMB + k0 + lseg, &As[c * 512]);
            gl_lds16(wob  + (size_t)(colBase + row) * EMB + k0 + lseg, &Bs[c * 512]);
        }
        __syncthreads();

        const int soff = ((quad ^ rxor) << 3);
        short8 af[4], bf[4];
        #pragma unroll
        for (int mi = 0; mi < 4; ++mi)
            af[mi] = *reinterpret_cast<const short8*>(
                &As[(wm + mi * 16 + c16) * 32 + soff]);
        #pragma unroll
        for (int ni = 0; ni < 4; ++ni)
            bf[ni] = *reinterpret_cast<const short8*>(
                &Bs[(wn + ni * 16 + c16) * 32 + soff]);

        #pragma unroll
        for (int mi = 0; mi < 4; ++mi)
            #pragma unroll
            for (int ni = 0; ni < 4; ++ni)
                acc[mi][ni] = __builtin_amdgcn_mfma_f32_16x16x32_bf16(
                    af[mi], bf[ni], acc[mi][ni], 0, 0, 0);
    }

    #pragma unroll
    for (int ni = 0; ni < 4; ++ni) {
        const int n_full = colBase + wn + ni * 16 + c16;
        const float bb = bias[n_full];
        #pragma unroll
        for (int mi = 0; mi < 4; ++mi) {
            #pragma unroll
            for (int r = 0; r < 4; ++r) {
                const int m_g = rowBase + wm + mi * 16 + quad * 4 + r;
                out[(size_t)m_g * EMB + n_full] = acc[mi][ni][r] + bb;
            }
        }
    }
}

// ---------------------------------------------------------------------------
extern "C" void kernel_launch(void* const* d_in, const int* in_sizes, int n_in,
                              void* d_out, int out_size, void* d_ws, size_t ws_size,
                              hipStream_t stream) {
    const float* query = (const float*)d_in[0];
    const float* key   = (const float*)d_in[1];
    const float* value = (const float*)d_in[2];
    const float* in_w  = (const float*)d_in[3];
    const float* in_b  = (const float*)d_in[4];
    const float* out_w = (const float*)d_in[5];
    const float* out_b = (const float*)d_in[6];

    const size_t PLANE = (size_t)BATCH * NHEAD * S_LEN * HDIM;  // 4194304
    unsigned short* xqb = (unsigned short*)d_ws;
    unsigned short* xkb = xqb + PLANE;
    unsigned short* xvb = xkb + PLANE;
    unsigned short* wib = xvb + PLANE;                 // 3*EMB*EMB
    unsigned short* wob = wib + (size_t)3 * EMB * EMB; // EMB*EMB
    unsigned short* qo  = wob + (size_t)EMB * EMB;
    unsigned short* ko  = qo + PLANE;
    unsigned short* vto = ko + PLANE;
    unsigned short* cw  = vto + PLANE;

    convert_kernel<<<8192, 256, 0, stream>>>(query, key, value, in_w, out_w,
                                             xqb, xkb, xvb, wib, wob);

    qkv_gemm_kernel<<<768, 256, 0, stream>>>(xqb, xkb, xvb, wib, in_b, qo, ko, vto);

    attn_mfma_kernel<<<1024, 256, 0, stream>>>(qo, ko, vto, cw);

    out_gemm_kernel<<<256, 256, 0, stream>>>(cw, wob, out_b, (float*)d_out);
}